// Round 10
// baseline (5455.968 us; speedup 1.0000x reference)
//
#include <hip/hip_runtime.h>
#include <math.h>

typedef __bf16 bf16_t;
typedef __bf16 bf16x8 __attribute__((ext_vector_type(8)));
typedef float f32x4 __attribute__((ext_vector_type(4)));
typedef int i32x4 __attribute__((ext_vector_type(4)));
typedef unsigned int u32;

#define HID 2048
#define NBATCH 16
#define SEQLEN 512
#define MTOT (NBATCH * SEQLEN)
#define NBLK 32
#define RTHREADS 512
#define LN_EPS 1e-5f
#define CHB 8                      // batches per chain
#define STW (CHB * HID)            // u32 per state buffer (16384)

// ================= GEMM: inp = x @ Wi^T + b  -> d_out (fp32) =================
// Also zeroes the 4 tagged-state buffers EVERY launch (graph-replay safety:
// stale tags from a previous invocation must never match).
__global__ __launch_bounds__(256) void gemm_proj(
    const float* __restrict__ X,
    const float* __restrict__ Wi,
    const float* __restrict__ bias,
    float* __restrict__ C,
    u32* __restrict__ st)          // 4 contiguous buffers = 65536 dwords
{
    __shared__ bf16_t lA[128 * 32];
    __shared__ bf16_t lB[128 * 32];
    const int tid = threadIdx.x;
    if (blockIdx.y == 0) {
        const int base = blockIdx.x * 256 + tid;   // 16 blocks x 256 thr
#pragma unroll
        for (int j = 0; j < 16; ++j)
            st[j * 4096 + base] = 0u;
    }
    const int lane = tid & 63;
    const int wv = tid >> 6;
    const int bn = blockIdx.x * 128;
    const int bm = blockIdx.y * 128;
    const int wr = (wv >> 1) * 64;
    const int wc = (wv & 1) * 64;

    f32x4 zero = {0.f, 0.f, 0.f, 0.f};
    f32x4 acc[4][4];
#pragma unroll
    for (int i = 0; i < 4; ++i)
#pragma unroll
        for (int j = 0; j < 4; ++j) acc[i][j] = zero;

    for (int k0 = 0; k0 < HID; k0 += 32) {
        __syncthreads();
#pragma unroll
        for (int c = 0; c < 2; ++c) {
            const int chunk = c * 256 + tid;      // 0..511
            const int row = chunk >> 2;           // 0..127
            const int kp = (chunk & 3) ^ (row & 3); // XOR-swizzled source chunk
            {
                const float* s = X + (size_t)(bm + row) * HID + k0 + kp * 8;
                float4 a0 = *(const float4*)s;
                float4 a1 = *(const float4*)(s + 4);
                bf16x8 v;
                v[0] = (bf16_t)a0.x; v[1] = (bf16_t)a0.y; v[2] = (bf16_t)a0.z; v[3] = (bf16_t)a0.w;
                v[4] = (bf16_t)a1.x; v[5] = (bf16_t)a1.y; v[6] = (bf16_t)a1.z; v[7] = (bf16_t)a1.w;
                *(bf16x8*)(lA + chunk * 8) = v;
            }
            {
                const float* s = Wi + (size_t)(bn + row) * HID + k0 + kp * 8;
                float4 a0 = *(const float4*)s;
                float4 a1 = *(const float4*)(s + 4);
                bf16x8 v;
                v[0] = (bf16_t)a0.x; v[1] = (bf16_t)a0.y; v[2] = (bf16_t)a0.z; v[3] = (bf16_t)a0.w;
                v[4] = (bf16_t)a1.x; v[5] = (bf16_t)a1.y; v[6] = (bf16_t)a1.z; v[7] = (bf16_t)a1.w;
                *(bf16x8*)(lB + chunk * 8) = v;
            }
        }
        __syncthreads();

        bf16x8 af[4], bfr[4];
#pragma unroll
        for (int i = 0; i < 4; ++i) {
            const int row = wr + i * 16 + (lane & 15);
            const int ck = (lane >> 4) ^ (row & 3);
            af[i] = *(const bf16x8*)(lA + row * 32 + ck * 8);
        }
#pragma unroll
        for (int j = 0; j < 4; ++j) {
            const int row = wc + j * 16 + (lane & 15);
            const int ck = (lane >> 4) ^ (row & 3);
            bfr[j] = *(const bf16x8*)(lB + row * 32 + ck * 8);
        }
#pragma unroll
        for (int i = 0; i < 4; ++i)
#pragma unroll
            for (int j = 0; j < 4; ++j)
                acc[i][j] = __builtin_amdgcn_mfma_f32_16x16x32_bf16(af[i], bfr[j], acc[i][j], 0, 0, 0);
    }

#pragma unroll
    for (int j = 0; j < 4; ++j) {
        const int col = bn + wc + j * 16 + (lane & 15);
        const float bv = bias[col];
#pragma unroll
        for (int i = 0; i < 4; ++i) {
#pragma unroll
            for (int r = 0; r < 4; ++r) {
                const int row = bm + wr + i * 16 + (lane >> 4) * 4 + r;
                C[(size_t)row * HID + col] = acc[i][j][r] + bv;
            }
        }
    }
}

// ================= Persistent recurrent kernel =================
// Dual-chain (batches 0-7 / 8-15, independent recurrences) + TAGGED DATA:
// state elem = u32 (low16 bf16, high16 = step tag). Producers fire ONE
// relaxed store (no drain, no flags, no polls). Consumers speculatively load
// ~a phase early and verify tags (==t); rare retry (spin one dword + reload).
// Overwrite-safety (ping-pong, no flags): a block stores tag t+1 only after
// ALL its waves verified tags==t from all blocks (verify precedes the phase
// barrier; stores follow it). Tag t+2 into this buffer would require someone
// to have verified tag t+1 from US first -> impossible while we're at t.
// Deadlock-free: verify waits only on strictly earlier steps.
// vmcnt discipline: per phase, stream = [cinX, Xloads x16, stY, ioY];
// verify uses vmcnt(2). Retry path drains to 0 and is self-healing.
__global__ __launch_bounds__(RTHREADS, 1) void recurrent(
    const float* __restrict__ Wr,
    const float* __restrict__ mask,
    const float* __restrict__ tau,
    float* __restrict__ io,
    u32* __restrict__ sA0, u32* __restrict__ sA1,
    u32* __restrict__ sB0, u32* __restrict__ sB1)
{
    const int tid = threadIdx.x;
    const int lane = tid & 63;
    const int wv = tid >> 6;          // K-eighth 0..7 (also update batch-row)
    const int colbase = blockIdx.x * 64;

    __shared__ float redA[8][8][64];
    __shared__ float redB[8][8][64];

    // ---- preload masked weights: 32 MFMA B-fragments per wave ----
    bf16x8 wf[32];
    {
        const int kb = wv * 256 + (lane >> 4) * 8;
#pragma unroll
        for (int ct = 0; ct < 4; ++ct) {
            const int gc = colbase + ct * 16 + (lane & 15);
#pragma unroll
            for (int kf = 0; kf < 8; ++kf) {
                const size_t off = (size_t)gc * HID + kb + kf * 32;
                float4 a0 = *(const float4*)(Wr + off);
                float4 a1 = *(const float4*)(Wr + off + 4);
                float4 m0 = *(const float4*)(mask + off);
                float4 m1 = *(const float4*)(mask + off + 4);
                bf16x8 v;
                v[0] = (bf16_t)(a0.x * m0.x); v[1] = (bf16_t)(a0.y * m0.y);
                v[2] = (bf16_t)(a0.z * m0.z); v[3] = (bf16_t)(a0.w * m0.w);
                v[4] = (bf16_t)(a1.x * m1.x); v[5] = (bf16_t)(a1.y * m1.y);
                v[6] = (bf16_t)(a1.z * m1.z); v[7] = (bf16_t)(a1.w * m1.w);
                wf[ct * 8 + kf] = v;
            }
        }
    }

    const int urow = wv;               // batch row within chain
    const int ucol = lane;
    const int gcol = colbase + ucol;
    const size_t SH = (size_t)SEQLEN * HID;
    float al;
    {
        float tv = fminf(fmaxf(tau[gcol], 1.0f), 20.0f);
        al = fminf(fmaxf(0.5f / tv, 0.0f), 1.0f);
    }
    const int batchA = urow, batchB = CHB + urow;

    // per-wave tagged-load element offset (u32 units)
    const int aoff = (lane & 7) * HID + wv * 256 + (lane >> 4) * 8;

    u32* const bufA[2] = { sA0, sA1 };
    u32* const bufB[2] = { sB0, sB1 };

#define SB __builtin_amdgcn_sched_barrier(0)
#define GL4(d, p, o) asm volatile("global_load_dwordx4 %0, %1, off offset:" #o " sc0 sc1" : "=v"(d) : "v"(p) : "memory")
#define LOADBURST(q, p) \
    GL4(q[0], p, 0);   GL4(q[1], p, 16);  GL4(q[2], p, 128); GL4(q[3], p, 144); \
    GL4(q[4], p, 256); GL4(q[5], p, 272); GL4(q[6], p, 384); GL4(q[7], p, 400); \
    GL4(q[8], p, 512); GL4(q[9], p, 528); GL4(q[10], p, 640); GL4(q[11], p, 656); \
    GL4(q[12], p, 768); GL4(q[13], p, 784); GL4(q[14], p, 896); GL4(q[15], p, 912)
#define STORE_T(p, v) asm volatile("global_store_dword %0, %1, off sc0 sc1" :: "v"(p), "v"(v) : "memory")
#define STORE_F(p, v) asm volatile("global_store_dword %0, %1, off" :: "v"(p), "v"(v) : "memory")
#define LOAD_F(d, p)  asm volatile("global_load_dword %0, %1, off" : "=v"(d) : "v"(p) : "memory")

    i32x4 q[16];
    float cinA_f, cinB_f;
    float s_oldA, s_oldB;

    // ---- prologue: step 0 both chains (state zero -> rec = 0) ----
    {
        float cA = io[(size_t)batchA * SH + gcol];
        float cB = io[(size_t)batchB * SH + gcol];
        float zA = fminf(fmaxf(cA, -15.f), 15.f);
        float zB = fminf(fmaxf(cB, -15.f), 15.f);
        const float eA = __expf(2.0f * zA), eB = __expf(2.0f * zB);
        float snA = fminf(fmaxf(al * ((eA - 1.0f) / (eA + 1.0f)), -1.0f), 1.0f);
        float snB = fminf(fmaxf(al * ((eB - 1.0f) / (eB + 1.0f)), -1.0f), 1.0f);
        union { bf16_t b[2]; u32 u; } pv;
        pv.b[1] = (bf16_t)0.f;
        pv.b[0] = (bf16_t)snA;
        u32 svA = (pv.u & 0xffffu) | (1u << 16);
        pv.b[0] = (bf16_t)snB;
        u32 svB = (pv.u & 0xffffu) | (1u << 16);
        STORE_T(sA0 + (size_t)urow * HID + gcol, svA);
        STORE_T(sB0 + (size_t)urow * HID + gcol, svB);
        asm volatile("s_waitcnt vmcnt(0)" ::: "memory"); SB;
        // stream tail for phase A(1): [cinA, Aloads x16, st, st]
        LOAD_F(cinA_f, io + (size_t)batchA * SH + HID + gcol);   // row 1
        LOADBURST(q, sA0 + aoff);
        STORE_F(io + (size_t)batchA * SH + gcol, snA);           // io row 0
        STORE_F(io + (size_t)batchB * SH + gcol, snB);
        s_oldA = snA; s_oldB = snB;
    }

#define MF(fr, kf) \
        acc0 = __builtin_amdgcn_mfma_f32_16x16x32_bf16(fr, wf[kf],      acc0, 0, 0, 0); \
        acc1 = __builtin_amdgcn_mfma_f32_16x16x32_bf16(fr, wf[8 + kf],  acc1, 0, 0, 0); \
        acc2 = __builtin_amdgcn_mfma_f32_16x16x32_bf16(fr, wf[16 + kf], acc2, 0, 0, 0); \
        acc3 = __builtin_amdgcn_mfma_f32_16x16x32_bf16(fr, wf[24 + kf], acc3, 0, 0, 0);
#define CHK2(i) (((q[2*(i)][0] ^ tgs) | (q[2*(i)][1] ^ tgs) | (q[2*(i)][2] ^ tgs) | (q[2*(i)][3] ^ tgs) | \
                  (q[2*(i)+1][0] ^ tgs) | (q[2*(i)+1][1] ^ tgs) | (q[2*(i)+1][2] ^ tgs) | (q[2*(i)+1][3] ^ tgs)) & (int)0xffff0000)
#define PACKF(fr, i) \
        fr.d[0] = (q[2*(i)][0] & 0xffff) | (q[2*(i)][1] << 16); \
        fr.d[1] = (q[2*(i)][2] & 0xffff) | (q[2*(i)][3] << 16); \
        fr.d[2] = (q[2*(i)+1][0] & 0xffff) | (q[2*(i)+1][1] << 16); \
        fr.d[3] = (q[2*(i)+1][2] & 0xffff) | (q[2*(i)+1][3] << 16);

    union uf { int d[4]; bf16x8 v; };

    for (int t = 1; t < SEQLEN; ++t) {
        const int tgs = t << 16;
        const int tn = (t < SEQLEN - 1) ? (t + 1) : t;

        // ================= PHASE A =================
        {
            const u32* tb = bufA[(t - 1) & 1] + aoff;
            asm volatile("s_waitcnt vmcnt(2)" ::: "memory"); SB;
            for (;;) {
                int bad = CHK2(0) | CHK2(1) | CHK2(2) | CHK2(3)
                        | CHK2(4) | CHK2(5) | CHK2(6) | CHK2(7);
                if (__ballot(bad != 0) == 0ull) break;
                int v;
                do {
                    asm volatile("global_load_dword %0, %1, off sc0 sc1\n\ts_waitcnt vmcnt(0)"
                                 : "=v"(v) : "v"(tb) : "memory");
                } while (__ballot((v >> 16) != t) != 0ull);
                LOADBURST(q, tb);
                asm volatile("s_waitcnt vmcnt(0)" ::: "memory"); SB;
            }
            uf f0, f1, f2, f3, f4, f5, f6, f7;
            PACKF(f0, 0) PACKF(f1, 1) PACKF(f2, 2) PACKF(f3, 3)
            PACKF(f4, 4) PACKF(f5, 5) PACKF(f6, 6) PACKF(f7, 7)
            f32x4 acc0 = {0.f,0.f,0.f,0.f}, acc1 = {0.f,0.f,0.f,0.f};
            f32x4 acc2 = {0.f,0.f,0.f,0.f}, acc3 = {0.f,0.f,0.f,0.f};
            MF(f0.v, 0) MF(f1.v, 1) MF(f2.v, 2) MF(f3.v, 3)
            MF(f4.v, 4) MF(f5.v, 5) MF(f6.v, 6) MF(f7.v, 7)
            if (lane < 32) {
                const int r0 = (lane >> 4) * 4;
                const int cA = lane & 15;
#pragma unroll
                for (int r = 0; r < 4; ++r) {
                    redA[wv][r0 + r][cA]      = acc0[r];
                    redA[wv][r0 + r][16 + cA] = acc1[r];
                    redA[wv][r0 + r][32 + cA] = acc2[r];
                    redA[wv][r0 + r][48 + cA] = acc3[r];
                }
            }
            asm volatile("s_waitcnt lgkmcnt(0)" ::: "memory"); SB;
            asm volatile("s_barrier" ::: "memory"); SB;

            // issue next-phase stream: [cinB(t), Bloads x16]
            LOAD_F(cinB_f, io + (size_t)batchB * SH + (size_t)t * HID + gcol);
            LOADBURST(q, bufB[(t - 1) & 1] + aoff);

            float rec = 0.f;
#pragma unroll
            for (int q8 = 0; q8 < 8; ++q8) rec += redA[q8][urow][ucol];
            float z = fminf(fmaxf(cinA_f + rec, -15.f), 15.f);
            const float e = __expf(2.0f * z);
            const float tg = (e - 1.0f) / (e + 1.0f);
            float sn = fminf(fmaxf(s_oldA + al * (tg - s_oldA), -1.0f), 1.0f);
            union { bf16_t b[2]; u32 u; } pv;
            pv.b[0] = (bf16_t)sn; pv.b[1] = (bf16_t)0.f;
            u32 sv = (pv.u & 0xffffu) | ((u32)(t + 1) << 16);
            STORE_T(bufA[t & 1] + (size_t)urow * HID + gcol, sv);
            STORE_F(io + (size_t)batchA * SH + (size_t)t * HID + gcol, sn);
            s_oldA = sn;
        }

        // ================= PHASE B =================
        {
            const u32* tb = bufB[(t - 1) & 1] + aoff;
            asm volatile("s_waitcnt vmcnt(2)" ::: "memory"); SB;
            for (;;) {
                int bad = CHK2(0) | CHK2(1) | CHK2(2) | CHK2(3)
                        | CHK2(4) | CHK2(5) | CHK2(6) | CHK2(7);
                if (__ballot(bad != 0) == 0ull) break;
                int v;
                do {
                    asm volatile("global_load_dword %0, %1, off sc0 sc1\n\ts_waitcnt vmcnt(0)"
                                 : "=v"(v) : "v"(tb) : "memory");
                } while (__ballot((v >> 16) != t) != 0ull);
                LOADBURST(q, tb);
                asm volatile("s_waitcnt vmcnt(0)" ::: "memory"); SB;
            }
            uf f0, f1, f2, f3, f4, f5, f6, f7;
            PACKF(f0, 0) PACKF(f1, 1) PACKF(f2, 2) PACKF(f3, 3)
            PACKF(f4, 4) PACKF(f5, 5) PACKF(f6, 6) PACKF(f7, 7)
            f32x4 acc0 = {0.f,0.f,0.f,0.f}, acc1 = {0.f,0.f,0.f,0.f};
            f32x4 acc2 = {0.f,0.f,0.f,0.f}, acc3 = {0.f,0.f,0.f,0.f};
            MF(f0.v, 0) MF(f1.v, 1) MF(f2.v, 2) MF(f3.v, 3)
            MF(f4.v, 4) MF(f5.v, 5) MF(f6.v, 6) MF(f7.v, 7)
            if (lane < 32) {
                const int r0 = (lane >> 4) * 4;
                const int cA = lane & 15;
#pragma unroll
                for (int r = 0; r < 4; ++r) {
                    redB[wv][r0 + r][cA]      = acc0[r];
                    redB[wv][r0 + r][16 + cA] = acc1[r];
                    redB[wv][r0 + r][32 + cA] = acc2[r];
                    redB[wv][r0 + r][48 + cA] = acc3[r];
                }
            }
            asm volatile("s_waitcnt lgkmcnt(0)" ::: "memory"); SB;
            asm volatile("s_barrier" ::: "memory"); SB;

            // issue next-phase stream: [cinA(t+1), Aloads(t+1) x16]
            LOAD_F(cinA_f, io + (size_t)batchA * SH + (size_t)tn * HID + gcol);
            LOADBURST(q, bufA[t & 1] + aoff);

            float rec = 0.f;
#pragma unroll
            for (int q8 = 0; q8 < 8; ++q8) rec += redB[q8][urow][ucol];
            float z = fminf(fmaxf(cinB_f + rec, -15.f), 15.f);
            const float e = __expf(2.0f * z);
            const float tg = (e - 1.0f) / (e + 1.0f);
            float sn = fminf(fmaxf(s_oldB + al * (tg - s_oldB), -1.0f), 1.0f);
            union { bf16_t b[2]; u32 u; } pv;
            pv.b[0] = (bf16_t)sn; pv.b[1] = (bf16_t)0.f;
            u32 sv = (pv.u & 0xffffu) | ((u32)(t + 1) << 16);
            STORE_T(bufB[t & 1] + (size_t)urow * HID + gcol, sv);
            STORE_F(io + (size_t)batchB * SH + (size_t)t * HID + gcol, sn);
            s_oldB = sn;
        }
    }
#undef MF
#undef CHK2
#undef PACKF
#undef SB
}

// ================= LayerNorm (in-place on d_out) =================
__global__ __launch_bounds__(256) void ln_kernel(
    float* __restrict__ io,
    const float* __restrict__ gamma,
    const float* __restrict__ beta)
{
    const size_t row = blockIdx.x;
    float* p = io + row * HID;
    const int tid = threadIdx.x;
    float4 v0 = *(const float4*)(p + tid * 4);
    float4 v1 = *(const float4*)(p + 1024 + tid * 4);
    float s  = v0.x + v0.y + v0.z + v0.w + v1.x + v1.y + v1.z + v1.w;
    float ss = v0.x * v0.x + v0.y * v0.y + v0.z * v0.z + v0.w * v0.w
             + v1.x * v1.x + v1.y * v1.y + v1.z * v1.z + v1.w * v1.w;
#pragma unroll
    for (int off = 32; off > 0; off >>= 1) {
        s  += __shfl_down(s, off, 64);
        ss += __shfl_down(ss, off, 64);
    }
    __shared__ float rs[4], rss[4];
    if ((tid & 63) == 0) { rs[tid >> 6] = s; rss[tid >> 6] = ss; }
    __syncthreads();
    s  = rs[0] + rs[1] + rs[2] + rs[3];
    ss = rss[0] + rss[1] + rss[2] + rss[3];
    const float mu = s * (1.f / HID);
    const float var = ss * (1.f / HID) - mu * mu;
    const float inv = rsqrtf(var + LN_EPS);
    const int c0 = tid * 4, c1 = 1024 + tid * 4;
    float4 g0 = *(const float4*)(gamma + c0);
    float4 g1 = *(const float4*)(gamma + c1);
    float4 b0 = *(const float4*)(beta + c0);
    float4 b1 = *(const float4*)(beta + c1);
    float4 o0, o1;
    o0.x = (v0.x - mu) * inv * g0.x + b0.x;
    o0.y = (v0.y - mu) * inv * g0.y + b0.y;
    o0.z = (v0.z - mu) * inv * g0.z + b0.z;
    o0.w = (v0.w - mu) * inv * g0.w + b0.w;
    o1.x = (v1.x - mu) * inv * g1.x + b1.x;
    o1.y = (v1.y - mu) * inv * g1.y + b1.y;
    o1.z = (v1.z - mu) * inv * g1.z + b1.z;
    o1.w = (v1.w - mu) * inv * g1.w + b1.w;
    *(float4*)(p + tid * 4) = o0;
    *(float4*)(p + 1024 + tid * 4) = o1;
}

extern "C" void kernel_launch(void* const* d_in, const int* in_sizes, int n_in,
                              void* d_out, int out_size, void* d_ws, size_t ws_size,
                              hipStream_t stream)
{
    const float* x     = (const float*)d_in[0];
    const float* Wi    = (const float*)d_in[1];
    const float* bias  = (const float*)d_in[2];
    const float* Wr    = (const float*)d_in[3];
    const float* mask  = (const float*)d_in[4];
    const float* tau   = (const float*)d_in[5];
    const float* gamma = (const float*)d_in[6];
    const float* beta  = (const float*)d_in[7];
    float* out = (float*)d_out;

    u32* base = (u32*)d_ws;
    u32* sA0 = base;
    u32* sA1 = base + STW;
    u32* sB0 = base + 2 * STW;
    u32* sB1 = base + 3 * STW;

    // 1) input projection -> d_out rows hold inp[b,t,:] (fp32); zeroes tag bufs
    gemm_proj<<<dim3(16, 64), 256, 0, stream>>>(x, Wi, bias, out, sA0);
    // 2) persistent dual-chain tagged recurrence
    recurrent<<<NBLK, RTHREADS, 0, stream>>>(Wr, mask, tau, out, sA0, sA1, sB0, sB1);
    // 3) layernorm in-place
    ln_kernel<<<MTOT, 256, 0, stream>>>(out, gamma, beta);
}

// Round 11
// 2531.611 us; speedup vs baseline: 2.1551x; 2.1551x over previous
//
#include <hip/hip_runtime.h>
#include <math.h>

typedef __bf16 bf16_t;
typedef __bf16 bf16x8 __attribute__((ext_vector_type(8)));
typedef float f32x4 __attribute__((ext_vector_type(4)));
typedef int i32x4 __attribute__((ext_vector_type(4)));
typedef unsigned int u32;

#define HID 2048
#define NBATCH 16
#define SEQLEN 512
#define MTOT (NBATCH * SEQLEN)
#define NBLK 32
#define RTHREADS 256
#define LN_EPS 1e-5f

// ================= GEMM: inp = x @ Wi^T + b  -> d_out (fp32) =================
__global__ __launch_bounds__(256) void gemm_proj(
    const float* __restrict__ X,
    const float* __restrict__ Wi,
    const float* __restrict__ bias,
    float* __restrict__ C,
    int* __restrict__ flags)
{
    __shared__ bf16_t lA[128 * 32];
    __shared__ bf16_t lB[128 * 32];
    const int tid = threadIdx.x;
    if (blockIdx.x == 0 && blockIdx.y == 0) {
        if (tid < NBLK) flags[tid] = 0;   // re-zero EVERY launch (graph replay safety)
    }
    const int lane = tid & 63;
    const int wv = tid >> 6;
    const int bn = blockIdx.x * 128;
    const int bm = blockIdx.y * 128;
    const int wr = (wv >> 1) * 64;
    const int wc = (wv & 1) * 64;

    f32x4 zero = {0.f, 0.f, 0.f, 0.f};
    f32x4 acc[4][4];
#pragma unroll
    for (int i = 0; i < 4; ++i)
#pragma unroll
        for (int j = 0; j < 4; ++j) acc[i][j] = zero;

    for (int k0 = 0; k0 < HID; k0 += 32) {
        __syncthreads();
#pragma unroll
        for (int c = 0; c < 2; ++c) {
            const int chunk = c * 256 + tid;      // 0..511
            const int row = chunk >> 2;           // 0..127
            const int kp = (chunk & 3) ^ (row & 3); // XOR-swizzled source chunk
            {
                const float* s = X + (size_t)(bm + row) * HID + k0 + kp * 8;
                float4 a0 = *(const float4*)s;
                float4 a1 = *(const float4*)(s + 4);
                bf16x8 v;
                v[0] = (bf16_t)a0.x; v[1] = (bf16_t)a0.y; v[2] = (bf16_t)a0.z; v[3] = (bf16_t)a0.w;
                v[4] = (bf16_t)a1.x; v[5] = (bf16_t)a1.y; v[6] = (bf16_t)a1.z; v[7] = (bf16_t)a1.w;
                *(bf16x8*)(lA + chunk * 8) = v;
            }
            {
                const float* s = Wi + (size_t)(bn + row) * HID + k0 + kp * 8;
                float4 a0 = *(const float4*)s;
                float4 a1 = *(const float4*)(s + 4);
                bf16x8 v;
                v[0] = (bf16_t)a0.x; v[1] = (bf16_t)a0.y; v[2] = (bf16_t)a0.z; v[3] = (bf16_t)a0.w;
                v[4] = (bf16_t)a1.x; v[5] = (bf16_t)a1.y; v[6] = (bf16_t)a1.z; v[7] = (bf16_t)a1.w;
                *(bf16x8*)(lB + chunk * 8) = v;
            }
        }
        __syncthreads();

        bf16x8 af[4], bfr[4];
#pragma unroll
        for (int i = 0; i < 4; ++i) {
            const int row = wr + i * 16 + (lane & 15);
            const int ck = (lane >> 4) ^ (row & 3);
            af[i] = *(const bf16x8*)(lA + row * 32 + ck * 8);
        }
#pragma unroll
        for (int j = 0; j < 4; ++j) {
            const int row = wc + j * 16 + (lane & 15);
            const int ck = (lane >> 4) ^ (row & 3);
            bfr[j] = *(const bf16x8*)(lB + row * 32 + ck * 8);
        }
#pragma unroll
        for (int i = 0; i < 4; ++i)
#pragma unroll
            for (int j = 0; j < 4; ++j)
                acc[i][j] = __builtin_amdgcn_mfma_f32_16x16x32_bf16(af[i], bfr[j], acc[i][j], 0, 0, 0);
    }

#pragma unroll
    for (int j = 0; j < 4; ++j) {
        const int col = bn + wc + j * 16 + (lane & 15);
        const float bv = bias[col];
#pragma unroll
        for (int i = 0; i < 4; ++i) {
#pragma unroll
            for (int r = 0; r < 4; ++r) {
                const int row = bm + wr + i * 16 + (lane >> 4) * 4 + r;
                C[(size_t)row * HID + col] = acc[i][j][r] + bv;
            }
        }
    }
}

// ================= Persistent recurrent kernel =================
// R7 structure (best measured: 32 blocks x 4 waves, wf[64] in AGPRs) plus:
//  - per-wave SUBSET gating: wave kq's K-quarter cols [kq*512,+512) come from
//    source blocks [kq*8, kq*8+8); it polls ONLY those 8 flags and proceeds
//    straight to its loads (no post-poll barrier). Union over 4 waves = all
//    32 blocks, and state writes happen after barrier B (joins all waves), so
//    the ping-pong overwrite-safety argument is unchanged.
//  - 2 barriers/step: B (lgkmcnt only, LDS write->read) and T (per-wave
//    vmcnt(0) drain -> publish). T also protects red[] reuse.
//  - cin(t+1) prefetch issued right after A-loads (hidden under MFMA).
__global__ __launch_bounds__(RTHREADS, 1) void recurrent(
    const float* __restrict__ Wr,
    const float* __restrict__ mask,
    const float* __restrict__ tau,
    float* __restrict__ io,      // d_out: holds inp (read rows t+1) -> states (write row t)
    bf16_t* __restrict__ st0,
    bf16_t* __restrict__ st1,
    int* __restrict__ flags)     // [32]
{
    const int tid = threadIdx.x;
    const int lane = tid & 63;
    const int wv = tid >> 6;          // K-quarter 0..3
    const int colbase = blockIdx.x * 64;

    __shared__ float red[4][16][68];  // [kq][batch][col] pad 68

    // ---- preload masked weights: 64 MFMA B-fragments per wave (AGPR-backed) ----
    bf16x8 wf[64];
    {
        const int kb = wv * 512 + (lane >> 4) * 8;
#pragma unroll
        for (int ct = 0; ct < 4; ++ct) {
            const int gc = colbase + ct * 16 + (lane & 15);
#pragma unroll
            for (int kf = 0; kf < 16; ++kf) {
                const size_t off = (size_t)gc * HID + kb + kf * 32;
                float4 a0 = *(const float4*)(Wr + off);
                float4 a1 = *(const float4*)(Wr + off + 4);
                float4 m0 = *(const float4*)(mask + off);
                float4 m1 = *(const float4*)(mask + off + 4);
                bf16x8 v;
                v[0] = (bf16_t)(a0.x * m0.x); v[1] = (bf16_t)(a0.y * m0.y);
                v[2] = (bf16_t)(a0.z * m0.z); v[3] = (bf16_t)(a0.w * m0.w);
                v[4] = (bf16_t)(a1.x * m1.x); v[5] = (bf16_t)(a1.y * m1.y);
                v[6] = (bf16_t)(a1.z * m1.z); v[7] = (bf16_t)(a1.w * m1.w);
                wf[ct * 16 + kf] = v;
            }
        }
    }

    // update mapping: 256 threads <-> 16 batches x 16 col-groups of 4
    const int row = tid >> 4;          // batch 0..15
    const int cg  = (tid & 15) * 4;    // col offset within block
    const int gcol = colbase + cg;
    float al[4];
#pragma unroll
    for (int j = 0; j < 4; ++j) {
        float tv = tau[gcol + j];
        tv = fminf(fmaxf(tv, 1.0f), 20.0f);
        al[j] = fminf(fmaxf(0.5f / tv, 0.0f), 1.0f);
    }

    float s_old[4] = {0.f, 0.f, 0.f, 0.f};
    union F4 { float4 v; float f[4]; };
    F4 cin; cin.v = *(const float4*)(io + (size_t)row * (SEQLEN * HID) + gcol);

    const int akb = wv * 512 + (lane >> 4) * 8;   // A-frag k offset
    const int src = (wv << 3) + (lane & 7);       // my 8 source flags
    bf16_t* cur = st0;
    bf16_t* nxt = st1;

    // ---- step 0: state zero -> rec = 0; store, full drain, publish ----
    {
        float sn[4]; F4 ov;
#pragma unroll
        for (int j = 0; j < 4; ++j) {
            float z = fminf(fmaxf(cin.f[j], -15.f), 15.f);
            const float e = __expf(2.0f * z);
            const float tg = (e - 1.0f) / (e + 1.0f);
            float s = al[j] * tg;
            s = fminf(fmaxf(s, -1.0f), 1.0f);
            sn[j] = s; ov.f[j] = s;
        }
        union { bf16_t b[2]; u32 u; } p0, p1;
        p0.b[0] = (bf16_t)sn[0]; p0.b[1] = (bf16_t)sn[1];
        p1.b[0] = (bf16_t)sn[2]; p1.b[1] = (bf16_t)sn[3];
        u32* sp = (u32*)(nxt + (size_t)row * HID + gcol);
        __hip_atomic_store(sp,     p0.u, __ATOMIC_RELAXED, __HIP_MEMORY_SCOPE_AGENT);
        __hip_atomic_store(sp + 1, p1.u, __ATOMIC_RELAXED, __HIP_MEMORY_SCOPE_AGENT);
        *(float4*)(io + (size_t)row * (SEQLEN * HID) + gcol) = ov.v;
#pragma unroll
        for (int j = 0; j < 4; ++j) s_old[j] = sn[j];
        cin.v = *(const float4*)(io + (size_t)row * (SEQLEN * HID) + HID + gcol);
        asm volatile("s_waitcnt vmcnt(0)" ::: "memory");
        __builtin_amdgcn_sched_barrier(0);
        asm volatile("s_barrier" ::: "memory");
        __builtin_amdgcn_sched_barrier(0);
        if (tid == 0)
            __hip_atomic_store(flags + (int)blockIdx.x, 1,
                               __ATOMIC_RELAXED, __HIP_MEMORY_SCOPE_AGENT);
        bf16_t* tmp = cur; cur = nxt; nxt = tmp;
    }

    for (int t = 1; t < SEQLEN; ++t) {
        // ---- per-wave subset gate: my 8 source blocks published step t ----
        {
            int v;
            do {
                v = __hip_atomic_load(flags + src, __ATOMIC_RELAXED, __HIP_MEMORY_SCOPE_AGENT);
            } while (__ballot(v < t) != 0ull);
        }
        __builtin_amdgcn_sched_barrier(0);

        // ---- device-coherent A-fragment loads (16 x 16B) + cin prefetch ----
        const bf16_t* ab = cur + (size_t)(lane & 15) * HID + akb;
        union uf { i32x4 i; bf16x8 v; } a[16];
        asm volatile("global_load_dwordx4 %0, %1, off sc0 sc1"            : "=v"(a[0].i)  : "v"(ab) : "memory");
        asm volatile("global_load_dwordx4 %0, %1, off offset:64 sc0 sc1"  : "=v"(a[1].i)  : "v"(ab) : "memory");
        asm volatile("global_load_dwordx4 %0, %1, off offset:128 sc0 sc1" : "=v"(a[2].i)  : "v"(ab) : "memory");
        asm volatile("global_load_dwordx4 %0, %1, off offset:192 sc0 sc1" : "=v"(a[3].i)  : "v"(ab) : "memory");
        asm volatile("global_load_dwordx4 %0, %1, off offset:256 sc0 sc1" : "=v"(a[4].i)  : "v"(ab) : "memory");
        asm volatile("global_load_dwordx4 %0, %1, off offset:320 sc0 sc1" : "=v"(a[5].i)  : "v"(ab) : "memory");
        asm volatile("global_load_dwordx4 %0, %1, off offset:384 sc0 sc1" : "=v"(a[6].i)  : "v"(ab) : "memory");
        asm volatile("global_load_dwordx4 %0, %1, off offset:448 sc0 sc1" : "=v"(a[7].i)  : "v"(ab) : "memory");
        asm volatile("global_load_dwordx4 %0, %1, off offset:512 sc0 sc1" : "=v"(a[8].i)  : "v"(ab) : "memory");
        asm volatile("global_load_dwordx4 %0, %1, off offset:576 sc0 sc1" : "=v"(a[9].i)  : "v"(ab) : "memory");
        asm volatile("global_load_dwordx4 %0, %1, off offset:640 sc0 sc1" : "=v"(a[10].i) : "v"(ab) : "memory");
        asm volatile("global_load_dwordx4 %0, %1, off offset:704 sc0 sc1" : "=v"(a[11].i) : "v"(ab) : "memory");
        asm volatile("global_load_dwordx4 %0, %1, off offset:768 sc0 sc1" : "=v"(a[12].i) : "v"(ab) : "memory");
        asm volatile("global_load_dwordx4 %0, %1, off offset:832 sc0 sc1" : "=v"(a[13].i) : "v"(ab) : "memory");
        asm volatile("global_load_dwordx4 %0, %1, off offset:896 sc0 sc1" : "=v"(a[14].i) : "v"(ab) : "memory");
        asm volatile("global_load_dwordx4 %0, %1, off offset:960 sc0 sc1" : "=v"(a[15].i) : "v"(ab) : "memory");
        // prefetch next-step input: lands under the MFMA phase
        const int tn = (t < SEQLEN - 1) ? (t + 1) : t;
        F4 cin_next;
        cin_next.v = *(const float4*)(io + (size_t)row * (SEQLEN * HID) + (size_t)tn * HID + gcol);

        f32x4 acc0 = {0.f,0.f,0.f,0.f}, acc1 = {0.f,0.f,0.f,0.f};
        f32x4 acc2 = {0.f,0.f,0.f,0.f}, acc3 = {0.f,0.f,0.f,0.f};

        asm volatile("s_waitcnt vmcnt(9)" ::: "memory");  // a0..a7 landed (cin + a8..15 fly)
        __builtin_amdgcn_sched_barrier(0);
#define MF(kf) \
        acc0 = __builtin_amdgcn_mfma_f32_16x16x32_bf16(a[kf].v, wf[kf],      acc0, 0, 0, 0); \
        acc1 = __builtin_amdgcn_mfma_f32_16x16x32_bf16(a[kf].v, wf[16 + kf], acc1, 0, 0, 0); \
        acc2 = __builtin_amdgcn_mfma_f32_16x16x32_bf16(a[kf].v, wf[32 + kf], acc2, 0, 0, 0); \
        acc3 = __builtin_amdgcn_mfma_f32_16x16x32_bf16(a[kf].v, wf[48 + kf], acc3, 0, 0, 0);
        MF(0) MF(1) MF(2) MF(3) MF(4) MF(5) MF(6) MF(7)
        asm volatile("s_waitcnt vmcnt(1)" ::: "memory");  // a8..a15 landed (cin may fly)
        __builtin_amdgcn_sched_barrier(0);
        MF(8) MF(9) MF(10) MF(11) MF(12) MF(13) MF(14) MF(15)
#undef MF

        // ---- LDS partials -> barrier B (lgkmcnt only) ----
        {
            const int r0 = (lane >> 4) * 4;
            const int cA = lane & 15;
#pragma unroll
            for (int r = 0; r < 4; ++r) {
                red[wv][r0 + r][cA]      = acc0[r];
                red[wv][r0 + r][16 + cA] = acc1[r];
                red[wv][r0 + r][32 + cA] = acc2[r];
                red[wv][r0 + r][48 + cA] = acc3[r];
            }
        }
        asm volatile("s_waitcnt lgkmcnt(0)" ::: "memory");
        __builtin_amdgcn_sched_barrier(0);
        asm volatile("s_barrier" ::: "memory");          // B
        __builtin_amdgcn_sched_barrier(0);

        F4 s0, s1, s2, s3;
        s0.v = *(const float4*)&red[0][row][cg];
        s1.v = *(const float4*)&red[1][row][cg];
        s2.v = *(const float4*)&red[2][row][cg];
        s3.v = *(const float4*)&red[3][row][cg];

        float sn[4]; F4 ov;
#pragma unroll
        for (int j = 0; j < 4; ++j) {
            const float rec = s0.f[j] + s1.f[j] + s2.f[j] + s3.f[j];
            float z = cin.f[j] + rec;
            z = fminf(fmaxf(z, -15.f), 15.f);
            const float e = __expf(2.0f * z);
            const float tg = (e - 1.0f) / (e + 1.0f);
            float s = s_old[j] + al[j] * (tg - s_old[j]);
            s = fminf(fmaxf(s, -1.0f), 1.0f);
            sn[j] = s; ov.f[j] = s;
        }

        // ---- state + io stores -> per-wave drain -> barrier T -> publish ----
        union { bf16_t b[2]; u32 u; } p0, p1;
        p0.b[0] = (bf16_t)sn[0]; p0.b[1] = (bf16_t)sn[1];
        p1.b[0] = (bf16_t)sn[2]; p1.b[1] = (bf16_t)sn[3];
        u32* sp = (u32*)(nxt + (size_t)row * HID + gcol);
        __hip_atomic_store(sp,     p0.u, __ATOMIC_RELAXED, __HIP_MEMORY_SCOPE_AGENT);
        __hip_atomic_store(sp + 1, p1.u, __ATOMIC_RELAXED, __HIP_MEMORY_SCOPE_AGENT);
        *(float4*)(io + (size_t)row * (SEQLEN * HID) + (size_t)t * HID + gcol) = ov.v;

        asm volatile("s_waitcnt vmcnt(0)" ::: "memory");
        __builtin_amdgcn_sched_barrier(0);
        asm volatile("s_barrier" ::: "memory");          // T
        __builtin_amdgcn_sched_barrier(0);
        if (t != SEQLEN - 1 && tid == 0)
            __hip_atomic_store(flags + (int)blockIdx.x, t + 1,
                               __ATOMIC_RELAXED, __HIP_MEMORY_SCOPE_AGENT);

#pragma unroll
        for (int j = 0; j < 4; ++j) s_old[j] = sn[j];
        cin = cin_next;
        bf16_t* tmp = cur; cur = nxt; nxt = tmp;
    }
}

// ================= LayerNorm (in-place on d_out) =================
__global__ __launch_bounds__(256) void ln_kernel(
    float* __restrict__ io,
    const float* __restrict__ gamma,
    const float* __restrict__ beta)
{
    const size_t row = blockIdx.x;
    float* p = io + row * HID;
    const int tid = threadIdx.x;
    float4 v0 = *(const float4*)(p + tid * 4);
    float4 v1 = *(const float4*)(p + 1024 + tid * 4);
    float s  = v0.x + v0.y + v0.z + v0.w + v1.x + v1.y + v1.z + v1.w;
    float ss = v0.x * v0.x + v0.y * v0.y + v0.z * v0.z + v0.w * v0.w
             + v1.x * v1.x + v1.y * v1.y + v1.z * v1.z + v1.w * v1.w;
#pragma unroll
    for (int off = 32; off > 0; off >>= 1) {
        s  += __shfl_down(s, off, 64);
        ss += __shfl_down(ss, off, 64);
    }
    __shared__ float rs[4], rss[4];
    if ((tid & 63) == 0) { rs[tid >> 6] = s; rss[tid >> 6] = ss; }
    __syncthreads();
    s  = rs[0] + rs[1] + rs[2] + rs[3];
    ss = rss[0] + rss[1] + rss[2] + rss[3];
    const float mu = s * (1.f / HID);
    const float var = ss * (1.f / HID) - mu * mu;
    const float inv = rsqrtf(var + LN_EPS);
    const int c0 = tid * 4, c1 = 1024 + tid * 4;
    float4 g0 = *(const float4*)(gamma + c0);
    float4 g1 = *(const float4*)(gamma + c1);
    float4 b0 = *(const float4*)(beta + c0);
    float4 b1 = *(const float4*)(beta + c1);
    float4 o0, o1;
    o0.x = (v0.x - mu) * inv * g0.x + b0.x;
    o0.y = (v0.y - mu) * inv * g0.y + b0.y;
    o0.z = (v0.z - mu) * inv * g0.z + b0.z;
    o0.w = (v0.w - mu) * inv * g0.w + b0.w;
    o1.x = (v1.x - mu) * inv * g1.x + b1.x;
    o1.y = (v1.y - mu) * inv * g1.y + b1.y;
    o1.z = (v1.z - mu) * inv * g1.z + b1.z;
    o1.w = (v1.w - mu) * inv * g1.w + b1.w;
    *(float4*)(p + tid * 4) = o0;
    *(float4*)(p + 1024 + tid * 4) = o1;
}

extern "C" void kernel_launch(void* const* d_in, const int* in_sizes, int n_in,
                              void* d_out, int out_size, void* d_ws, size_t ws_size,
                              hipStream_t stream)
{
    const float* x     = (const float*)d_in[0];
    const float* Wi    = (const float*)d_in[1];
    const float* bias  = (const float*)d_in[2];
    const float* Wr    = (const float*)d_in[3];
    const float* mask  = (const float*)d_in[4];
    const float* tau   = (const float*)d_in[5];
    const float* gamma = (const float*)d_in[6];
    const float* beta  = (const float*)d_in[7];
    float* out = (float*)d_out;

    bf16_t* st0 = (bf16_t*)d_ws;
    bf16_t* st1 = st0 + (size_t)NBATCH * HID;
    int* flags  = (int*)(st1 + (size_t)NBATCH * HID);

    // 1) input projection -> d_out rows hold inp[b,t,:] (fp32); also zeroes flags
    gemm_proj<<<dim3(16, 64), 256, 0, stream>>>(x, Wi, bias, out, flags);
    // 2) persistent recurrence: overwrites d_out rows with pre-LN states
    recurrent<<<NBLK, RTHREADS, 0, stream>>>(Wr, mask, tau, out, st0, st1, flags);
    // 3) layernorm in-place
    ln_kernel<<<MTOT, 256, 0, stream>>>(out, gamma, beta);
}